// Round 1
// baseline (14289.194 us; speedup 1.0000x reference)
//
#include <hip/hip_runtime.h>
#include <hip/hip_bf16.h>
#include <cstdint>

#define NLAYER 4
#define DMODEL 1024
#define NHEAD 16
#define DHEAD 64
#define DINNER 4096
#define QLEN 512
#define MLEN 512
#define KLEN (QLEN + MLEN)
#define BATCH 4
#define ND (NHEAD * DHEAD) /* 1024 */

// ---------------- embedding gather: h[q,b,:] = word_emb[tok[b,q],:] ----------------
__global__ __launch_bounds__(256) void embed_kernel(
    const int* __restrict__ tok, const float* __restrict__ emb, float* __restrict__ h)
{
  const int q = blockIdx.x, b = blockIdx.y, t = threadIdx.x;
  const int id = tok[b * QLEN + q];
  const float4* src = (const float4*)(emb + (size_t)id * DMODEL);
  float4* dst = (float4*)(h + ((size_t)q * BATCH + b) * DMODEL);
  dst[t] = src[t]; // 256 threads x 4 floats = 1024
}

// ---------------- sinusoidal pos emb: pe[k,:] for pos = K-1-k ----------------
__global__ __launch_bounds__(256) void posemb_kernel(float* __restrict__ pe)
{
  const int k = blockIdx.x, t = threadIdx.x;
  const float pos = (float)(KLEN - 1 - k);
  for (int i = t; i < DMODEL / 2; i += 256) {
    const float inv_freq = powf(10000.0f, -(float)(2 * i) / (float)DMODEL);
    const float a = pos * inv_freq;
    pe[(size_t)k * DMODEL + i] = sinf(a);
    pe[(size_t)k * DMODEL + DMODEL / 2 + i] = cosf(a);
  }
}

// ---------------- generic NT GEMM: C[M,N] = A[M,Kd] @ W[N,Kd]^T (+bias,relu) -------
// A rows < splitRow come from A0, rows >= splitRow from A1 (when A1 != nullptr).
#define BM 64
#define BN 64
#define BK 16
__global__ __launch_bounds__(256) void gemm_nt_kernel(
    const float* __restrict__ A0, const float* __restrict__ A1, int splitRow,
    const float* __restrict__ W, float* __restrict__ C,
    const float* __restrict__ bias, int relu, int M, int N, int Kd)
{
  __shared__ float As[BK][BM + 4];
  __shared__ float Ws[BK][BN + 4];
  const int bm = blockIdx.x * BM, bn = blockIdx.y * BN;
  const int t = threadIdx.x;
  const int tx = t & 15, ty = t >> 4;       // 16x16 thread grid, 4x4 micro-tile
  const int lr = t >> 2, lc = (t & 3) * 4;  // loader: row 0..63, k-offset {0,4,8,12}
  float acc[4][4] = {};
  const int ga = bm + lr;
  const float* Arow = (A1 == nullptr || ga < splitRow)
                          ? (A0 + (size_t)ga * Kd)
                          : (A1 + (size_t)(ga - splitRow) * Kd);
  const float* Wrow = W + (size_t)(bn + lr) * Kd;
  for (int k0 = 0; k0 < Kd; k0 += BK) {
    const float4 av = *(const float4*)(Arow + k0 + lc);
    const float4 wv = *(const float4*)(Wrow + k0 + lc);
    As[lc + 0][lr] = av.x; As[lc + 1][lr] = av.y; As[lc + 2][lr] = av.z; As[lc + 3][lr] = av.w;
    Ws[lc + 0][lr] = wv.x; Ws[lc + 1][lr] = wv.y; Ws[lc + 2][lr] = wv.z; Ws[lc + 3][lr] = wv.w;
    __syncthreads();
#pragma unroll
    for (int kk = 0; kk < BK; ++kk) {
      float a[4], w[4];
#pragma unroll
      for (int x = 0; x < 4; ++x) a[x] = As[kk][ty * 4 + x];
#pragma unroll
      for (int x = 0; x < 4; ++x) w[x] = Ws[kk][tx * 4 + x];
#pragma unroll
      for (int mi = 0; mi < 4; ++mi)
#pragma unroll
        for (int ni = 0; ni < 4; ++ni)
          acc[mi][ni] = fmaf(a[mi], w[ni], acc[mi][ni]);
    }
    __syncthreads();
  }
#pragma unroll
  for (int mi = 0; mi < 4; ++mi) {
    const int row = bm + ty * 4 + mi;
#pragma unroll
    for (int ni = 0; ni < 4; ++ni) {
      const int col = bn + tx * 4 + ni;
      float v = acc[mi][ni];
      if (bias) v += bias[col];
      if (relu) v = fmaxf(v, 0.0f);
      C[(size_t)row * N + col] = v;
    }
  }
}

// ---------------- fused rel-attention: one block per (i, n, b) ----------------
// score[j] = scale*( (q_i+rwb_n)·k_j + (q_i+rrb_n)·r[j-i+Q-1] ) for j <= i+M
// then softmax over j, then vec = P·V.
__global__ __launch_bounds__(256) void attn_kernel(
    const float* __restrict__ qkv, const float* __restrict__ rbuf,
    const float* __restrict__ rwb, const float* __restrict__ rrb,
    float* __restrict__ vec)
{
  const int i = blockIdx.x;   // query row
  const int n = blockIdx.y;   // head
  const int b = blockIdx.z;   // batch
  const int t = threadIdx.x;
  __shared__ float qa[DHEAD], qb[DHEAD];
  __shared__ float sc[KLEN];
  __shared__ float red[256];
  const int jmax = i + MLEN;  // inclusive last unmasked key
  const float* qrow = qkv + ((size_t)(MLEN + i) * BATCH + b) * (3 * ND) + n * DHEAD;
  if (t < DHEAD) {
    const float qv = qrow[t];
    qa[t] = qv + rwb[n * DHEAD + t];
    qb[t] = qv + rrb[n * DHEAD + t];
  }
  __syncthreads();
  float lmax = -3.0e38f;
  for (int j = t; j <= jmax; j += 256) {
    const float* krow = qkv + ((size_t)j * BATCH + b) * (3 * ND) + ND + n * DHEAD;
    const float* rrow = rbuf + (size_t)(j - i + QLEN - 1) * ND + n * DHEAD;
    float s = 0.0f;
#pragma unroll
    for (int d = 0; d < DHEAD; ++d) s = fmaf(qa[d], krow[d], s);
#pragma unroll
    for (int d = 0; d < DHEAD; ++d) s = fmaf(qb[d], rrow[d], s);
    s *= 0.125f;
    sc[j] = s;
    lmax = fmaxf(lmax, s);
  }
  red[t] = lmax;
  __syncthreads();
  for (int w = 128; w > 0; w >>= 1) {
    if (t < w) red[t] = fmaxf(red[t], red[t + w]);
    __syncthreads();
  }
  const float m = red[0];
  __syncthreads();
  float lsum = 0.0f;
  for (int j = t; j <= jmax; j += 256) {
    const float p = expf(sc[j] - m);
    sc[j] = p;
    lsum += p;
  }
  red[t] = lsum;
  __syncthreads();
  for (int w = 128; w > 0; w >>= 1) {
    if (t < w) red[t] += red[t + w];
    __syncthreads();
  }
  const float inv = 1.0f / red[0];
  __syncthreads();
  const int d = t & (DHEAD - 1), c = t >> 6; // 4 j-chunks x 64 d-lanes
  float acc = 0.0f;
  for (int j = c; j <= jmax; j += 4)
    acc = fmaf(sc[j], qkv[((size_t)j * BATCH + b) * (3 * ND) + 2 * ND + n * DHEAD + d], acc);
  red[t] = acc;
  __syncthreads();
  if (c == 0) {
    const float v = red[d] + red[64 + d] + red[128 + d] + red[192 + d];
    vec[((size_t)i * BATCH + b) * ND + n * DHEAD + d] = v * inv;
  }
}

// ---------------- fused residual + LayerNorm (in-place on h) ----------------
__global__ __launch_bounds__(256) void ln_residual_kernel(
    float* __restrict__ h, const float* __restrict__ delta,
    const float* __restrict__ g, const float* __restrict__ bb)
{
  const int row = blockIdx.x, t = threadIdx.x;
  __shared__ float xs[DMODEL];
  __shared__ float red[256];
  float s = 0.0f;
  for (int d = t; d < DMODEL; d += 256) {
    const float v = h[(size_t)row * DMODEL + d] + delta[(size_t)row * DMODEL + d];
    xs[d] = v;
    s += v;
  }
  red[t] = s;
  __syncthreads();
  for (int w = 128; w > 0; w >>= 1) {
    if (t < w) red[t] += red[t + w];
    __syncthreads();
  }
  const float mean = red[0] * (1.0f / DMODEL);
  __syncthreads();
  float vs = 0.0f;
  for (int d = t; d < DMODEL; d += 256) {
    const float dv = xs[d] - mean;
    vs = fmaf(dv, dv, vs);
  }
  red[t] = vs;
  __syncthreads();
  for (int w = 128; w > 0; w >>= 1) {
    if (t < w) red[t] += red[t + w];
    __syncthreads();
  }
  const float rstd = rsqrtf(red[0] * (1.0f / DMODEL) + 1e-5f);
  for (int d = t; d < DMODEL; d += 256)
    h[(size_t)row * DMODEL + d] = (xs[d] - mean) * rstd * g[d] + bb[d];
}

// ---------------- output transpose [Q,B,D] -> [B,Q,D] ----------------
__global__ __launch_bounds__(256) void out_kernel(
    const float* __restrict__ h, float* __restrict__ out)
{
  const int q = blockIdx.x, b = blockIdx.y, t = threadIdx.x;
  const float4* src = (const float4*)(h + ((size_t)q * BATCH + b) * DMODEL);
  float4* dst = (float4*)(out + ((size_t)b * QLEN + q) * DMODEL);
  dst[t] = src[t];
}

extern "C" void kernel_launch(void* const* d_in, const int* in_sizes, int n_in,
                              void* d_out, int out_size, void* d_ws, size_t ws_size,
                              hipStream_t stream)
{
  const int*   tok  = (const int*)d_in[0];
  const float* mems = (const float*)d_in[1];
  const float* wemb = (const float*)d_in[2];
  const float* qkvw = (const float*)d_in[3];
  const float* ow   = (const float*)d_in[4];
  const float* rw   = (const float*)d_in[5];
  const float* rwb  = (const float*)d_in[6];
  const float* rrb  = (const float*)d_in[7];
  const float* ln1g = (const float*)d_in[8];
  const float* ln1b = (const float*)d_in[9];
  const float* ffw1 = (const float*)d_in[10];
  const float* ffb1 = (const float*)d_in[11];
  const float* ffw2 = (const float*)d_in[12];
  const float* ffb2 = (const float*)d_in[13];
  const float* ln2g = (const float*)d_in[14];
  const float* ln2b = (const float*)d_in[15];

  float* ws = (float*)d_ws;
  float* h   = ws;                                  // [2048,1024]  (q*B+b rows)
  float* pe  = h   + (size_t)2048 * 1024;           // [1024,1024]
  float* qkv = pe  + (size_t)1024 * 1024;           // [4096,3072]  (k*B+b rows)
  float* rb  = qkv + (size_t)4096 * 3072;           // [1024,1024]
  float* vec = rb  + (size_t)1024 * 1024;           // [2048,1024]
  float* ffh = vec + (size_t)2048 * 1024;           // [2048,4096]
  float* tmp = ffh + (size_t)2048 * 4096;           // [2048,1024]

  embed_kernel<<<dim3(QLEN, BATCH), 256, 0, stream>>>(tok, wemb, h);
  posemb_kernel<<<KLEN, 256, 0, stream>>>(pe);

  for (int l = 0; l < NLAYER; ++l) {
    // qkv = cat(mems[l], h) @ qkv_w[l]^T   rows: k*B+b
    gemm_nt_kernel<<<dim3(4096 / BM, 3072 / BN), 256, 0, stream>>>(
        mems + (size_t)l * MLEN * BATCH * DMODEL, h, MLEN * BATCH,
        qkvw + (size_t)l * 3 * ND * DMODEL, qkv, nullptr, 0, 4096, 3 * ND, DMODEL);
    // r = pe @ r_w[l]^T
    gemm_nt_kernel<<<dim3(KLEN / BM, ND / BN), 256, 0, stream>>>(
        pe, nullptr, 1 << 30, rw + (size_t)l * ND * DMODEL, rb, nullptr, 0,
        KLEN, ND, DMODEL);
    // fused rel-shift attention + softmax + PV
    attn_kernel<<<dim3(QLEN, NHEAD, BATCH), 256, 0, stream>>>(
        qkv, rb, rwb + (size_t)l * ND, rrb + (size_t)l * ND, vec);
    // o-proj
    gemm_nt_kernel<<<dim3(2048 / BM, 1024 / BN), 256, 0, stream>>>(
        vec, nullptr, 1 << 30, ow + (size_t)l * DMODEL * ND, tmp, nullptr, 0,
        2048, DMODEL, ND);
    ln_residual_kernel<<<2048, 256, 0, stream>>>(
        h, tmp, ln1g + (size_t)l * DMODEL, ln1b + (size_t)l * DMODEL);
    // FFN
    gemm_nt_kernel<<<dim3(2048 / BM, 4096 / BN), 256, 0, stream>>>(
        h, nullptr, 1 << 30, ffw1 + (size_t)l * DINNER * DMODEL, ffh,
        ffb1 + (size_t)l * DINNER, 1, 2048, DINNER, DMODEL);
    gemm_nt_kernel<<<dim3(2048 / BM, 1024 / BN), 256, 0, stream>>>(
        ffh, nullptr, 1 << 30, ffw2 + (size_t)l * DMODEL * DINNER, tmp,
        ffb2 + (size_t)l * DMODEL, 0, 2048, DMODEL, DINNER);
    ln_residual_kernel<<<2048, 256, 0, stream>>>(
        h, tmp, ln2g + (size_t)l * DMODEL, ln2b + (size_t)l * DMODEL);
  }

  out_kernel<<<dim3(QLEN, BATCH), 256, 0, stream>>>(h, (float*)d_out);
}

// Round 2
// 6260.989 us; speedup vs baseline: 2.2823x; 2.2823x over previous
//
#include <hip/hip_runtime.h>
#include <hip/hip_bf16.h>
#include <cstdint>

#define NLAYER 4
#define DMODEL 1024
#define NHEAD 16
#define DHEAD 64
#define DINNER 4096
#define QLEN 512
#define MLEN 512
#define KLEN (QLEN + MLEN)
#define BATCH 4
#define ND (NHEAD * DHEAD) /* 1024 */

// ---------------- embedding gather: h[q,b,:] = word_emb[tok[b,q],:] ----------------
__global__ __launch_bounds__(256) void embed_kernel(
    const int* __restrict__ tok, const float* __restrict__ emb, float* __restrict__ h)
{
  const int q = blockIdx.x, b = blockIdx.y, t = threadIdx.x;
  const int id = tok[b * QLEN + q];
  const float4* src = (const float4*)(emb + (size_t)id * DMODEL);
  float4* dst = (float4*)(h + ((size_t)q * BATCH + b) * DMODEL);
  dst[t] = src[t];
}

// ---------------- sinusoidal pos emb: pe[k,:] for pos = K-1-k ----------------
__global__ __launch_bounds__(256) void posemb_kernel(float* __restrict__ pe)
{
  const int k = blockIdx.x, t = threadIdx.x;
  const float pos = (float)(KLEN - 1 - k);
  for (int i = t; i < DMODEL / 2; i += 256) {
    const float inv_freq = powf(10000.0f, -(float)(2 * i) / (float)DMODEL);
    const float a = pos * inv_freq;
    pe[(size_t)k * DMODEL + i] = sinf(a);
    pe[(size_t)k * DMODEL + DMODEL / 2 + i] = cosf(a);
  }
}

// ---------------- generic NT GEMM: C[M,N] = A[M,Kd] @ W[N,Kd]^T (+bias,relu) -------
#define BM 64
#define BN 64
#define BK 16
__global__ __launch_bounds__(256) void gemm_nt_kernel(
    const float* __restrict__ A0, const float* __restrict__ A1, int splitRow,
    const float* __restrict__ W, float* __restrict__ C,
    const float* __restrict__ bias, int relu, int M, int N, int Kd)
{
  __shared__ float As[BK][BM + 4];
  __shared__ float Ws[BK][BN + 4];
  const int bm = blockIdx.x * BM, bn = blockIdx.y * BN;
  const int t = threadIdx.x;
  const int tx = t & 15, ty = t >> 4;
  const int lr = t >> 2, lc = (t & 3) * 4;
  float acc[4][4] = {};
  const int ga = bm + lr;
  const float* Arow = (A1 == nullptr || ga < splitRow)
                          ? (A0 + (size_t)ga * Kd)
                          : (A1 + (size_t)(ga - splitRow) * Kd);
  const float* Wrow = W + (size_t)(bn + lr) * Kd;
  for (int k0 = 0; k0 < Kd; k0 += BK) {
    const float4 av = *(const float4*)(Arow + k0 + lc);
    const float4 wv = *(const float4*)(Wrow + k0 + lc);
    As[lc + 0][lr] = av.x; As[lc + 1][lr] = av.y; As[lc + 2][lr] = av.z; As[lc + 3][lr] = av.w;
    Ws[lc + 0][lr] = wv.x; Ws[lc + 1][lr] = wv.y; Ws[lc + 2][lr] = wv.z; Ws[lc + 3][lr] = wv.w;
    __syncthreads();
#pragma unroll
    for (int kk = 0; kk < BK; ++kk) {
      float a[4], w[4];
#pragma unroll
      for (int x = 0; x < 4; ++x) a[x] = As[kk][ty * 4 + x];
#pragma unroll
      for (int x = 0; x < 4; ++x) w[x] = Ws[kk][tx * 4 + x];
#pragma unroll
      for (int mi = 0; mi < 4; ++mi)
#pragma unroll
        for (int ni = 0; ni < 4; ++ni)
          acc[mi][ni] = fmaf(a[mi], w[ni], acc[mi][ni]);
    }
    __syncthreads();
  }
#pragma unroll
  for (int mi = 0; mi < 4; ++mi) {
    const int row = bm + ty * 4 + mi;
#pragma unroll
    for (int ni = 0; ni < 4; ++ni) {
      const int col = bn + tx * 4 + ni;
      float v = acc[mi][ni];
      if (bias) v += bias[col];
      if (relu) v = fmaxf(v, 0.0f);
      C[(size_t)row * N + col] = v;
    }
  }
}

// ---------------- qa/qb prep: qa = q + r_w_bias, qb = q + r_r_bias ----------------
__global__ __launch_bounds__(256) void qprep_kernel(
    const float* __restrict__ qkv, const float* __restrict__ rwb,
    const float* __restrict__ rrb, float* __restrict__ qa, float* __restrict__ qb)
{
  const int row = blockIdx.x;  // i*B+b, 0..2047
  const int t = threadIdx.x;
  const float4 qv = *(const float4*)(qkv + ((size_t)row + MLEN * BATCH) * (3 * ND) + t * 4);
  const float4 wv = *(const float4*)(rwb + t * 4);
  const float4 rv = *(const float4*)(rrb + t * 4);
  float4 a, b2;
  a.x = qv.x + wv.x; a.y = qv.y + wv.y; a.z = qv.z + wv.z; a.w = qv.w + wv.w;
  b2.x = qv.x + rv.x; b2.y = qv.y + rv.y; b2.z = qv.z + rv.z; b2.w = qv.w + rv.w;
  *(float4*)(qa + (size_t)row * ND + t * 4) = a;
  *(float4*)(qb + (size_t)row * ND + t * 4) = b2;
}

// ------- batched attention NT GEMM: per (nn,b): C[i,x] = A_i . B_x (Kd=64) -------
// shift_add=0: S[i,j] = acc         (AC term, x=j over keys)
// shift_add=1: S[i, x+i-(Q-1)] += acc   (BD term, x=s over pos; rel-shift in store)
__global__ __launch_bounds__(256) void attn_nt_gemm(
    const float* __restrict__ A, const float* __restrict__ Bm, float* __restrict__ S,
    int a_rstride, int b_rstride, int b_off_bmult, int b_off_const,
    int n_base, int shift_add)
{
  __shared__ float As[16][68];
  __shared__ float Bs[16][68];
  const int i0 = blockIdx.x * 64, j0 = blockIdx.y * 64;
  const int nn = blockIdx.z >> 2, b = blockIdx.z & 3;
  const int n = n_base + nn;
  const int t = threadIdx.x;
  const int tx = t & 15, ty = t >> 4;
  const int lr = t >> 2, lc = (t & 3) * 4;
  const float* Ab = A + (size_t)b * ND + n * 64;
  const float* Bb = Bm + (size_t)b * b_off_bmult + b_off_const + n * 64;
  float* Sb = S + ((size_t)nn * BATCH + b) * QLEN * KLEN;
  float acc[4][4] = {};
  for (int k0 = 0; k0 < 64; k0 += 16) {
    const float4 av = *(const float4*)(Ab + (size_t)(i0 + lr) * a_rstride + k0 + lc);
    const float4 bv = *(const float4*)(Bb + (size_t)(j0 + lr) * b_rstride + k0 + lc);
    As[lc + 0][lr] = av.x; As[lc + 1][lr] = av.y; As[lc + 2][lr] = av.z; As[lc + 3][lr] = av.w;
    Bs[lc + 0][lr] = bv.x; Bs[lc + 1][lr] = bv.y; Bs[lc + 2][lr] = bv.z; Bs[lc + 3][lr] = bv.w;
    __syncthreads();
#pragma unroll
    for (int kk = 0; kk < 16; ++kk) {
      float a[4], w[4];
#pragma unroll
      for (int x = 0; x < 4; ++x) a[x] = As[kk][ty * 4 + x];
#pragma unroll
      for (int x = 0; x < 4; ++x) w[x] = Bs[kk][tx * 4 + x];
#pragma unroll
      for (int mi = 0; mi < 4; ++mi)
#pragma unroll
        for (int ni = 0; ni < 4; ++ni)
          acc[mi][ni] = fmaf(a[mi], w[ni], acc[mi][ni]);
    }
    __syncthreads();
  }
  if (!shift_add) {
#pragma unroll
    for (int mi = 0; mi < 4; ++mi) {
      const int i = i0 + ty * 4 + mi;
#pragma unroll
      for (int ni = 0; ni < 4; ++ni)
        Sb[(size_t)i * KLEN + j0 + tx * 4 + ni] = acc[mi][ni];
    }
  } else {
#pragma unroll
    for (int mi = 0; mi < 4; ++mi) {
      const int i = i0 + ty * 4 + mi;
#pragma unroll
      for (int ni = 0; ni < 4; ++ni) {
        const int j = (j0 + tx * 4 + ni) + i - (QLEN - 1);
        if (j >= 0) Sb[(size_t)i * KLEN + j] += acc[mi][ni];
      }
    }
  }
}

// -------- row softmax over j<=i+M with scale; zeros masked tail --------
__global__ __launch_bounds__(256) void attn_softmax(float* __restrict__ S)
{
  const int i = blockIdx.x, nn = blockIdx.y, b = blockIdx.z;
  const int t = threadIdx.x;
  float* row = S + ((size_t)nn * BATCH + b) * QLEN * KLEN + (size_t)i * KLEN;
  const int jmax = i + MLEN;
  __shared__ float red[256];
  float4 v = ((const float4*)row)[t];
  float x[4];
  const int j4 = t * 4;
  x[0] = (j4 + 0 <= jmax) ? v.x * 0.125f : -INFINITY;
  x[1] = (j4 + 1 <= jmax) ? v.y * 0.125f : -INFINITY;
  x[2] = (j4 + 2 <= jmax) ? v.z * 0.125f : -INFINITY;
  x[3] = (j4 + 3 <= jmax) ? v.w * 0.125f : -INFINITY;
  float lm = fmaxf(fmaxf(x[0], x[1]), fmaxf(x[2], x[3]));
  red[t] = lm;
  __syncthreads();
  for (int w = 128; w > 0; w >>= 1) {
    if (t < w) red[t] = fmaxf(red[t], red[t + w]);
    __syncthreads();
  }
  const float m = red[0];
  __syncthreads();
  float p[4], s = 0.0f;
#pragma unroll
  for (int e = 0; e < 4; ++e) { p[e] = expf(x[e] - m); s += p[e]; }
  red[t] = s;
  __syncthreads();
  for (int w = 128; w > 0; w >>= 1) {
    if (t < w) red[t] += red[t + w];
    __syncthreads();
  }
  const float inv = 1.0f / red[0];
  float4 o;
  o.x = p[0] * inv; o.y = p[1] * inv; o.z = p[2] * inv; o.w = p[3] * inv;
  ((float4*)row)[t] = o;
}

// -------- batched PV GEMM (NN): vec[i, n*64+d] = sum_j P[i,j] * V[j,d] --------
__global__ __launch_bounds__(256) void attn_pv_gemm(
    const float* __restrict__ S, const float* __restrict__ qkv,
    float* __restrict__ vec, int n_base)
{
  __shared__ float Ps[16][68];
  __shared__ float Vs[16][68];
  const int i0 = blockIdx.x * 64;
  const int nn = blockIdx.y, b = blockIdx.z;
  const int n = n_base + nn;
  const int t = threadIdx.x;
  const int tx = t & 15, ty = t >> 4;
  const int lr = t >> 2, lc = (t & 3) * 4;     // P loader: row i, k-offset
  const int lr2 = t >> 4, lc2 = (t & 15) * 4;  // V loader: row j, d-offset
  const float* Sb = S + ((size_t)nn * BATCH + b) * QLEN * KLEN;
  const float* Vb = qkv + (size_t)b * (3 * ND) + 2 * ND + n * 64;
  float acc[4][4] = {};
  const int jlim = i0 + 63 + MLEN;  // last j with nonzero P in this i-tile
  for (int j0 = 0; j0 <= jlim; j0 += 16) {
    const float4 pv = *(const float4*)(Sb + (size_t)(i0 + lr) * KLEN + j0 + lc);
    const float4 vv = *(const float4*)(Vb + (size_t)(j0 + lr2) * (BATCH * 3 * ND) + lc2);
    Ps[lc + 0][lr] = pv.x; Ps[lc + 1][lr] = pv.y; Ps[lc + 2][lr] = pv.z; Ps[lc + 3][lr] = pv.w;
    Vs[lr2][lc2 + 0] = vv.x; Vs[lr2][lc2 + 1] = vv.y; Vs[lr2][lc2 + 2] = vv.z; Vs[lr2][lc2 + 3] = vv.w;
    __syncthreads();
#pragma unroll
    for (int kk = 0; kk < 16; ++kk) {
      float a[4], w[4];
#pragma unroll
      for (int x = 0; x < 4; ++x) a[x] = Ps[kk][ty * 4 + x];
#pragma unroll
      for (int x = 0; x < 4; ++x) w[x] = Vs[kk][tx * 4 + x];
#pragma unroll
      for (int mi = 0; mi < 4; ++mi)
#pragma unroll
        for (int ni = 0; ni < 4; ++ni)
          acc[mi][ni] = fmaf(a[mi], w[ni], acc[mi][ni]);
    }
    __syncthreads();
  }
#pragma unroll
  for (int mi = 0; mi < 4; ++mi) {
    const int row = i0 + ty * 4 + mi;
#pragma unroll
    for (int ni = 0; ni < 4; ++ni)
      vec[((size_t)row * BATCH + b) * ND + n * 64 + tx * 4 + ni] = acc[mi][ni];
  }
}

// ---------------- fused residual + LayerNorm (in-place on h) ----------------
__global__ __launch_bounds__(256) void ln_residual_kernel(
    float* __restrict__ h, const float* __restrict__ delta,
    const float* __restrict__ g, const float* __restrict__ bb)
{
  const int row = blockIdx.x, t = threadIdx.x;
  __shared__ float xs[DMODEL];
  __shared__ float red[256];
  float s = 0.0f;
  for (int d = t; d < DMODEL; d += 256) {
    const float v = h[(size_t)row * DMODEL + d] + delta[(size_t)row * DMODEL + d];
    xs[d] = v;
    s += v;
  }
  red[t] = s;
  __syncthreads();
  for (int w = 128; w > 0; w >>= 1) {
    if (t < w) red[t] += red[t + w];
    __syncthreads();
  }
  const float mean = red[0] * (1.0f / DMODEL);
  __syncthreads();
  float vs = 0.0f;
  for (int d = t; d < DMODEL; d += 256) {
    const float dv = xs[d] - mean;
    vs = fmaf(dv, dv, vs);
  }
  red[t] = vs;
  __syncthreads();
  for (int w = 128; w > 0; w >>= 1) {
    if (t < w) red[t] += red[t + w];
    __syncthreads();
  }
  const float rstd = rsqrtf(red[0] * (1.0f / DMODEL) + 1e-5f);
  for (int d = t; d < DMODEL; d += 256)
    h[(size_t)row * DMODEL + d] = (xs[d] - mean) * rstd * g[d] + bb[d];
}

// ---------------- output transpose [Q,B,D] -> [B,Q,D] ----------------
__global__ __launch_bounds__(256) void out_kernel(
    const float* __restrict__ h, float* __restrict__ out)
{
  const int q = blockIdx.x, b = blockIdx.y, t = threadIdx.x;
  const float4* src = (const float4*)(h + ((size_t)q * BATCH + b) * DMODEL);
  float4* dst = (float4*)(out + ((size_t)b * QLEN + q) * DMODEL);
  dst[t] = src[t];
}

extern "C" void kernel_launch(void* const* d_in, const int* in_sizes, int n_in,
                              void* d_out, int out_size, void* d_ws, size_t ws_size,
                              hipStream_t stream)
{
  const int*   tok  = (const int*)d_in[0];
  const float* mems = (const float*)d_in[1];
  const float* wemb = (const float*)d_in[2];
  const float* qkvw = (const float*)d_in[3];
  const float* ow   = (const float*)d_in[4];
  const float* rw   = (const float*)d_in[5];
  const float* rwb  = (const float*)d_in[6];
  const float* rrb  = (const float*)d_in[7];
  const float* ln1g = (const float*)d_in[8];
  const float* ln1b = (const float*)d_in[9];
  const float* ffw1 = (const float*)d_in[10];
  const float* ffb1 = (const float*)d_in[11];
  const float* ffw2 = (const float*)d_in[12];
  const float* ffb2 = (const float*)d_in[13];
  const float* ln2g = (const float*)d_in[14];
  const float* ln2b = (const float*)d_in[15];

  float* ws = (float*)d_ws;
  float* h   = ws;                                  // [2048,1024]
  float* pe  = h   + (size_t)2048 * 1024;           // [1024,1024]
  float* qkv = pe  + (size_t)1024 * 1024;           // [4096,3072]
  float* rb  = qkv + (size_t)4096 * 3072;           // [1024,1024]
  float* vec = rb  + (size_t)1024 * 1024;           // [2048,1024]
  float* ffh = vec + (size_t)2048 * 1024;           // [2048,4096]
  float* tmp = ffh + (size_t)2048 * 4096;           // [2048,1024]
  float* qa  = tmp + (size_t)2048 * 1024;           // [2048,1024]
  float* qb  = qa  + (size_t)2048 * 1024;           // [2048,1024]
  float* S   = qb  + (size_t)2048 * 1024;           // [4,4,512,1024] per head-chunk

  embed_kernel<<<dim3(QLEN, BATCH), 256, 0, stream>>>(tok, wemb, h);
  posemb_kernel<<<KLEN, 256, 0, stream>>>(pe);

  for (int l = 0; l < NLAYER; ++l) {
    gemm_nt_kernel<<<dim3(4096 / BM, 3072 / BN), 256, 0, stream>>>(
        mems + (size_t)l * MLEN * BATCH * DMODEL, h, MLEN * BATCH,
        qkvw + (size_t)l * 3 * ND * DMODEL, qkv, nullptr, 0, 4096, 3 * ND, DMODEL);
    gemm_nt_kernel<<<dim3(KLEN / BM, ND / BN), 256, 0, stream>>>(
        pe, nullptr, 1 << 30, rw + (size_t)l * ND * DMODEL, rb, nullptr, 0,
        KLEN, ND, DMODEL);

    qprep_kernel<<<2048, 256, 0, stream>>>(
        qkv, rwb + (size_t)l * ND, rrb + (size_t)l * ND, qa, qb);
    for (int ng = 0; ng < NHEAD / 4; ++ng) {
      // AC: S[i,j] = qa_i . k_j
      attn_nt_gemm<<<dim3(8, 16, 16), 256, 0, stream>>>(
          qa, qkv, S, BATCH * ND, BATCH * 3 * ND, 3 * ND, ND, ng * 4, 0);
      // BD: S[i, s+i-511] += qb_i . r_s
      attn_nt_gemm<<<dim3(8, 16, 16), 256, 0, stream>>>(
          qb, rb, S, BATCH * ND, ND, 0, 0, ng * 4, 1);
      attn_softmax<<<dim3(QLEN, 4, BATCH), 256, 0, stream>>>(S);
      attn_pv_gemm<<<dim3(8, 4, BATCH), 256, 0, stream>>>(S, qkv, vec, ng * 4);
    }

    gemm_nt_kernel<<<dim3(2048 / BM, 1024 / BN), 256, 0, stream>>>(
        vec, nullptr, 1 << 30, ow + (size_t)l * DMODEL * ND, tmp, nullptr, 0,
        2048, DMODEL, ND);
    ln_residual_kernel<<<2048, 256, 0, stream>>>(
        h, tmp, ln1g + (size_t)l * DMODEL, ln1b + (size_t)l * DMODEL);
    gemm_nt_kernel<<<dim3(2048 / BM, 4096 / BN), 256, 0, stream>>>(
        h, nullptr, 1 << 30, ffw1 + (size_t)l * DINNER * DMODEL, ffh,
        ffb1 + (size_t)l * DINNER, 1, 2048, DINNER, DMODEL);
    gemm_nt_kernel<<<dim3(2048 / BM, 1024 / BN), 256, 0, stream>>>(
        ffh, nullptr, 1 << 30, ffw2 + (size_t)l * DMODEL * DINNER, tmp,
        ffb2 + (size_t)l * DMODEL, 0, 2048, DMODEL, DINNER);
    ln_residual_kernel<<<2048, 256, 0, stream>>>(
        h, tmp, ln2g + (size_t)l * DMODEL, ln2b + (size_t)l * DMODEL);
  }

  out_kernel<<<dim3(QLEN, BATCH), 256, 0, stream>>>(h, (float*)d_out);
}

// Round 4
// 1817.866 us; speedup vs baseline: 7.8604x; 3.4441x over previous
//
#include <hip/hip_runtime.h>
#include <cstdint>

#define NLAYER 4
#define DMODEL 1024
#define NHEAD 16
#define DHEAD 64
#define DINNER 4096
#define QLEN 512
#define MLEN 512
#define KLEN (QLEN + MLEN)
#define BATCH 4
#define ND (NHEAD * DHEAD)

typedef unsigned short u16;
typedef __attribute__((ext_vector_type(8))) short short8;
typedef __attribute__((ext_vector_type(4))) float f32x4;

__device__ __forceinline__ u16 f2b(float x) {
  unsigned u = __builtin_bit_cast(unsigned, x);
  return (u16)((u + 0x7fffu + ((u >> 16) & 1u)) >> 16);
}
__device__ __forceinline__ float b2f(u16 h) {
  return __builtin_bit_cast(float, (unsigned)h << 16);
}

// ---------------- f32 -> bf16 bulk convert (n multiple of 2048) ----------------
__global__ __launch_bounds__(256) void conv_bf16(
    const float* __restrict__ s, u16* __restrict__ d, int n8)
{
  const int i = blockIdx.x * 256 + threadIdx.x;
  if (i >= n8) return;
  const float4 a = ((const float4*)s)[2 * i], b = ((const float4*)s)[2 * i + 1];
  union { u16 u[8]; float4 v; } p;
  p.u[0] = f2b(a.x); p.u[1] = f2b(a.y); p.u[2] = f2b(a.z); p.u[3] = f2b(a.w);
  p.u[4] = f2b(b.x); p.u[5] = f2b(b.y); p.u[6] = f2b(b.z); p.u[7] = f2b(b.w);
  ((float4*)d)[i] = p.v;
}

// ---------------- embedding gather: writes h (f32) and h_bf (bf16) ----------------
__global__ __launch_bounds__(256) void embed_kernel(
    const int* __restrict__ tok, const float* __restrict__ emb,
    float* __restrict__ h, u16* __restrict__ hb)
{
  const int q = blockIdx.x, b = blockIdx.y, t = threadIdx.x;
  const int id = tok[b * QLEN + q];
  const float4 v = ((const float4*)(emb + (size_t)id * DMODEL))[t];
  const size_t row = (size_t)q * BATCH + b;
  ((float4*)(h + row * DMODEL))[t] = v;
  union { u16 u[4]; float2 f; } p;
  p.u[0] = f2b(v.x); p.u[1] = f2b(v.y); p.u[2] = f2b(v.z); p.u[3] = f2b(v.w);
  *(float2*)(hb + row * DMODEL + t * 4) = p.f;
}

// ---------------- sinusoidal pos emb (bf16 out) ----------------
__global__ __launch_bounds__(256) void posemb_kernel(u16* __restrict__ pe)
{
  const int k = blockIdx.x, t = threadIdx.x;
  const float pos = (float)(KLEN - 1 - k);
  for (int i = t; i < DMODEL / 2; i += 256) {
    const float inv_freq = powf(10000.0f, -(float)(2 * i) / (float)DMODEL);
    const float a = pos * inv_freq;
    pe[(size_t)k * DMODEL + i] = f2b(sinf(a));
    pe[(size_t)k * DMODEL + DMODEL / 2 + i] = f2b(cosf(a));
  }
}

// ---------------- MFMA NT GEMM: C[M,N] = A @ B^T, bf16 in, f32 acc ----------------
// MF = m-fragments per wave (2 or 4). BM = MF*32, BN = 128. 4 waves (2x2).
// z-batched: off = (z&3)*azb + (z>>2)*azn per operand.
template<int MF, int OUTBF, int RELU, int BIAS>
__global__ __launch_bounds__(256) void mgemm(
    const u16* __restrict__ A, const u16* __restrict__ B, void* __restrict__ Cp,
    const float* __restrict__ bias, int Kd,
    long sa, long sb, long sc,
    long azb, long azn, long bzb, long bzn, long czb, long czn)
{
  constexpr int BM = MF * 32;
  __shared__ u16 As[BM][40];
  __shared__ u16 Bs[128][40];
  const int z = blockIdx.z, zb = z & 3, zn = z >> 2;
  A += (size_t)zb * azb + (size_t)zn * azn;
  B += (size_t)zb * bzb + (size_t)zn * bzn;
  const size_t bm = (size_t)blockIdx.x * BM, bn = (size_t)blockIdx.y * 128;
  const int t = threadIdx.x;
  const int wave = t >> 6, lane = t & 63;
  const int wm = (wave >> 1) * (MF * 16), wn = (wave & 1) * 64;
  const int lrow = lane & 15, lk = lane >> 4;
  const int srow = t >> 2, skc = (t & 3) * 8;
  const u16* Ap = A + (bm + srow) * sa + skc;
  const u16* Bp = B + (bn + srow) * sb + skc;
  f32x4 acc[MF][4] = {};
  for (int k0 = 0; k0 < Kd; k0 += 32) {
    float4 a0, a1;
    a0 = *(const float4*)(Ap + k0);
    if (MF == 4) a1 = *(const float4*)(Ap + 64 * sa + k0);
    const float4 b0 = *(const float4*)(Bp + k0);
    const float4 b1 = *(const float4*)(Bp + 64 * sb + k0);
    __syncthreads();
    if (srow < BM) *(float4*)&As[srow][skc] = a0;
    if (MF == 4) *(float4*)&As[(srow + 64) & (BM - 1)][skc] = a1;
    *(float4*)&Bs[srow][skc] = b0;
    *(float4*)&Bs[srow + 64][skc] = b1;
    __syncthreads();
    short8 af[MF], bf[4];
#pragma unroll
    for (int x = 0; x < MF; ++x) af[x] = *(const short8*)&As[wm + x * 16 + lrow][lk * 8];
#pragma unroll
    for (int x = 0; x < 4; ++x) bf[x] = *(const short8*)&Bs[wn + x * 16 + lrow][lk * 8];
#pragma unroll
    for (int mi = 0; mi < MF; ++mi)
#pragma unroll
      for (int ni = 0; ni < 4; ++ni)
        acc[mi][ni] = __builtin_amdgcn_mfma_f32_16x16x32_bf16(af[mi], bf[ni], acc[mi][ni], 0, 0, 0);
  }
  const size_t row0 = bm + wm + lk * 4;
  const size_t col0 = bn + wn + lrow;
  if (OUTBF) {
    u16* C = (u16*)Cp + (size_t)zb * czb + (size_t)zn * czn;
#pragma unroll
    for (int mi = 0; mi < MF; ++mi)
#pragma unroll
      for (int r = 0; r < 4; ++r) {
        const size_t row = row0 + mi * 16 + r;
#pragma unroll
        for (int ni = 0; ni < 4; ++ni) {
          float v = acc[mi][ni][r];
          if (BIAS) v += bias[col0 + ni * 16];
          if (RELU) v = fmaxf(v, 0.0f);
          C[row * sc + col0 + ni * 16] = f2b(v);
        }
      }
  } else {
    float* C = (float*)Cp + (size_t)zb * czb + (size_t)zn * czn;
#pragma unroll
    for (int mi = 0; mi < MF; ++mi)
#pragma unroll
      for (int r = 0; r < 4; ++r) {
        const size_t row = row0 + mi * 16 + r;
#pragma unroll
        for (int ni = 0; ni < 4; ++ni) {
          float v = acc[mi][ni][r];
          if (BIAS) v += bias[col0 + ni * 16];
          if (RELU) v = fmaxf(v, 0.0f);
          C[row * sc + col0 + ni * 16] = v;
        }
      }
  }
}

// ---------------- PV GEMM: BM=128, N=64, per-block causal K early-stop ----------------
__global__ __launch_bounds__(256) void mgemm_pv(
    const u16* __restrict__ Pm, const u16* __restrict__ Vm, u16* __restrict__ Om,
    int Kd, long sa, long sb, long sc,
    long azb, long azn, long bzb, long bzn, long czb, long czn)
{
  __shared__ u16 As[128][40];
  __shared__ u16 Bs[64][40];
  const int z = blockIdx.z, zb = z & 3, zn = z >> 2;
  const u16* A = Pm + (size_t)zb * azb + (size_t)zn * azn;
  const u16* B = Vm + (size_t)zb * bzb + (size_t)zn * bzn;
  u16* C = Om + (size_t)zb * czb + (size_t)zn * czn;
  const int bm = blockIdx.x * 128;
  const int Ke = (Kd < bm + 640) ? Kd : bm + 640;
  const int t = threadIdx.x, wave = t >> 6, lane = t & 63;
  const int wm = wave * 32;
  const int lrow = lane & 15, lk = lane >> 4;
  const int srow = t >> 2, skc = (t & 3) * 8;
  f32x4 acc[2][4] = {};
  for (int k0 = 0; k0 < Ke; k0 += 32) {
    const float4 a0 = *(const float4*)(A + (size_t)(bm + srow) * sa + k0 + skc);
    const float4 a1 = *(const float4*)(A + (size_t)(bm + srow + 64) * sa + k0 + skc);
    float4 b0;
    if (srow < 64) b0 = *(const float4*)(B + (size_t)srow * sb + k0 + skc);
    __syncthreads();
    *(float4*)&As[srow][skc] = a0;
    *(float4*)&As[srow + 64][skc] = a1;
    if (srow < 64) *(float4*)&Bs[srow][skc] = b0;
    __syncthreads();
    short8 af[2], bf[4];
#pragma unroll
    for (int x = 0; x < 2; ++x) af[x] = *(const short8*)&As[wm + x * 16 + lrow][lk * 8];
#pragma unroll
    for (int x = 0; x < 4; ++x) bf[x] = *(const short8*)&Bs[x * 16 + lrow][lk * 8];
#pragma unroll
    for (int mi = 0; mi < 2; ++mi)
#pragma unroll
      for (int ni = 0; ni < 4; ++ni)
        acc[mi][ni] = __builtin_amdgcn_mfma_f32_16x16x32_bf16(af[mi], bf[ni], acc[mi][ni], 0, 0, 0);
  }
#pragma unroll
  for (int mi = 0; mi < 2; ++mi)
#pragma unroll
    for (int r = 0; r < 4; ++r) {
      const size_t row = bm + wm + mi * 16 + lk * 4 + r;
#pragma unroll
      for (int ni = 0; ni < 4; ++ni)
        C[row * sc + lrow + ni * 16] = f2b(acc[mi][ni][r]);
    }
}

// ---------------- qa/qb prep: q(bf16) + biases -> qa,qb (bf16, [b][i][nd]) ----------
__global__ __launch_bounds__(256) void qprep_kernel(
    const u16* __restrict__ qkvb, const float* __restrict__ rwb,
    const float* __restrict__ rrb, u16* __restrict__ qa, u16* __restrict__ qb)
{
  const int i = blockIdx.x, b = blockIdx.y, t = threadIdx.x;
  const int c = t * 4;
  const size_t src = ((size_t)(QLEN + i) * BATCH + b) * (3 * ND) + c;
  const size_t dst = ((size_t)b * QLEN + i) * ND + c;
  union { u16 u[4]; float2 f; } qi, oa, ob;
  qi.f = *(const float2*)(qkvb + src);
#pragma unroll
  for (int e = 0; e < 4; ++e) {
    const float q = b2f(qi.u[e]);
    oa.u[e] = f2b(q + rwb[c + e]);
    ob.u[e] = f2b(q + rrb[c + e]);
  }
  *(float2*)(qa + dst) = oa.f;
  *(float2*)(qb + dst) = ob.f;
}

// ---------------- V transpose: qkv V -> Vt[b][n][d][j] (bf16) ----------------
__global__ __launch_bounds__(256) void vtrans_kernel(
    const u16* __restrict__ qkvb, u16* __restrict__ Vt)
{
  __shared__ u16 T[64][72];
  const int j0 = blockIdx.x * 64;
  const int bn = blockIdx.y, b = bn >> 4, n = bn & 15;
  const int t = threadIdx.x;
  const int jl = t >> 3, ch = t & 7;
#pragma unroll
  for (int p = 0; p < 2; ++p) {
    const int jj = p * 32 + jl;
    const float4 v = *(const float4*)(qkvb + ((size_t)(j0 + jj) * BATCH + b) * (3 * ND)
                                      + 2 * ND + n * 64 + ch * 8);
    *(float4*)&T[jj][ch * 8] = v;
  }
  __syncthreads();
#pragma unroll
  for (int p = 0; p < 2; ++p) {
    const int dd = p * 32 + jl;
    union { u16 u[8]; float4 v; } o;
#pragma unroll
    for (int e = 0; e < 8; ++e) o.u[e] = T[ch * 8 + e][dd];
    *(float4*)(Vt + ((size_t)(b * 16 + n) * 64 + dd) * 1024 + j0 + ch * 8) = o.v;
  }
}

// -------- softmax: score = 0.125*(AC[i,j] + BD[i, j-i+511]); P (bf16) into S_AC ----
__global__ __launch_bounds__(256) void attn_softmax(
    const float* __restrict__ AC, const float* __restrict__ BD, u16* __restrict__ Pout)
{
  const int i = blockIdx.x, nn = blockIdx.y, b = blockIdx.z;
  const int t = threadIdx.x;
  const size_t ro = (size_t)(nn * 4 + b) * QLEN + i;
  const float* ac = AC + ro * KLEN;
  const float* bd = BD + ro * KLEN + (QLEN - 1) - i;
  u16* pr = Pout + ro * 2048;
  __shared__ float red[256];
  const int jmax = i + MLEN;
  const int j4 = t * 4;
  const float4 a4 = *(const float4*)(ac + j4);
  float x[4];
#pragma unroll
  for (int e = 0; e < 4; ++e) {
    const int j = j4 + e;
    float v = -INFINITY;
    if (j <= jmax) v = (((const float*)&a4)[e] + bd[j]) * 0.125f;
    x[e] = v;
  }
  float lm = fmaxf(fmaxf(x[0], x[1]), fmaxf(x[2], x[3]));
  red[t] = lm;
  __syncthreads();
  for (int w = 128; w > 0; w >>= 1) {
    if (t < w) red[t] = fmaxf(red[t], red[t + w]);
    __syncthreads();
  }
  const float m = red[0];
  __syncthreads();
  float p[4], s = 0.0f;
#pragma unroll
  for (int e = 0; e < 4; ++e) { p[e] = expf(x[e] - m); s += p[e]; }
  red[t] = s;
  __syncthreads();
  for (int w = 128; w > 0; w >>= 1) {
    if (t < w) red[t] += red[t + w];
    __syncthreads();
  }
  const float inv = 1.0f / red[0];
  union { u16 u[4]; float2 f; } o;
#pragma unroll
  for (int e = 0; e < 4; ++e) o.u[e] = f2b(p[e] * inv);
  *(float2*)(pr + j4) = o.f;
}

// ---------------- fused residual + LayerNorm; writes h (f32) and h_bf ----------------
__global__ __launch_bounds__(256) void ln_residual_kernel(
    float* __restrict__ h, u16* __restrict__ hb, const float* __restrict__ delta,
    const float* __restrict__ g, const float* __restrict__ bb)
{
  const int row = blockIdx.x, t = threadIdx.x;
  __shared__ float xs[DMODEL];
  __shared__ float red[256];
  float s = 0.0f;
  for (int d = t; d < DMODEL; d += 256) {
    const float v = h[(size_t)row * DMODEL + d] + delta[(size_t)row * DMODEL + d];
    xs[d] = v;
    s += v;
  }
  red[t] = s;
  __syncthreads();
  for (int w = 128; w > 0; w >>= 1) {
    if (t < w) red[t] += red[t + w];
    __syncthreads();
  }
  const float mean = red[0] * (1.0f / DMODEL);
  __syncthreads();
  float vs = 0.0f;
  for (int d = t; d < DMODEL; d += 256) {
    const float dv = xs[d] - mean;
    vs = fmaf(dv, dv, vs);
  }
  red[t] = vs;
  __syncthreads();
  for (int w = 128; w > 0; w >>= 1) {
    if (t < w) red[t] += red[t + w];
    __syncthreads();
  }
  const float rstd = rsqrtf(red[0] * (1.0f / DMODEL) + 1e-5f);
  for (int d = t; d < DMODEL; d += 256) {
    const float o = (xs[d] - mean) * rstd * g[d] + bb[d];
    h[(size_t)row * DMODEL + d] = o;
    hb[(size_t)row * DMODEL + d] = f2b(o);
  }
}

// ---------------- output transpose [Q,B,D] -> [B,Q,D] ----------------
__global__ __launch_bounds__(256) void out_kernel(
    const float* __restrict__ h, float* __restrict__ out)
{
  const int q = blockIdx.x, b = blockIdx.y, t = threadIdx.x;
  const float4* src = (const float4*)(h + ((size_t)q * BATCH + b) * DMODEL);
  float4* dst = (float4*)(out + ((size_t)b * QLEN + q) * DMODEL);
  dst[t] = src[t];
}

extern "C" void kernel_launch(void* const* d_in, const int* in_sizes, int n_in,
                              void* d_out, int out_size, void* d_ws, size_t ws_size,
                              hipStream_t stream)
{
  const int*   tok  = (const int*)d_in[0];
  const float* mems = (const float*)d_in[1];
  const float* wemb = (const float*)d_in[2];
  const float* qkvw = (const float*)d_in[3];
  const float* ow   = (const float*)d_in[4];
  const float* rw   = (const float*)d_in[5];
  const float* rwb  = (const float*)d_in[6];
  const float* rrb  = (const float*)d_in[7];
  const float* ln1g = (const float*)d_in[8];
  const float* ln1b = (const float*)d_in[9];
  const float* ffw1 = (const float*)d_in[10];
  const float* ffb1 = (const float*)d_in[11];
  const float* ffw2 = (const float*)d_in[12];
  const float* ffb2 = (const float*)d_in[13];
  const float* ln2g = (const float*)d_in[14];
  const float* ln2b = (const float*)d_in[15];

  float* h    = (float*)d_ws;                 // [2048][1024] f32
  float* S_AC = h + 2097152;                  // [16][512][1024] f32 (P bf16 strided in)
  float* S_BD = S_AC + 8388608;               // [16][512][1024] f32
  float* tmp  = S_BD;                         // alias (dead after softmax)
  u16* cat_bf = (u16*)(S_BD + 8388608);       // [4096][1024]
  u16* h_bf   = cat_bf + 2097152;
  u16* qkv_bf = cat_bf + 4194304;             // [4096][3072]
  u16* ffh_bf = qkv_bf;                       // alias (qkv dead after attention)
  u16* pe_bf  = qkv_bf + 12582912;            // [1024][1024]
  u16* rb_bf  = pe_bf + 1048576;              // [1024][1024]
  u16* qa_bf  = rb_bf + 1048576;              // [4][512][1024]
  u16* qb_bf  = qa_bf + 2097152;
  u16* Vt     = qb_bf + 2097152;              // [4][16][64][1024]
  u16* vec_bf = Vt + 4194304;                 // [2048][1024]
  u16* wq = vec_bf + 2097152;                 // [3072][1024]
  u16* wo = wq + 3145728;
  u16* wr = wo + 1048576;
  u16* w1 = wr + 1048576;                     // [4096][1024]
  u16* w2 = w1 + 4194304;                     // [1024][4096]

  embed_kernel<<<dim3(QLEN, BATCH), 256, 0, stream>>>(tok, wemb, h, h_bf);
  posemb_kernel<<<KLEN, 256, 0, stream>>>(pe_bf);

#define CONV(src, dst, n) conv_bf16<<<(n) / 2048, 256, 0, stream>>>(src, dst, (n) / 8)

  for (int l = 0; l < NLAYER; ++l) {
    CONV(mems + (size_t)l * 2097152, cat_bf, 2097152);
    CONV(qkvw + (size_t)l * 3145728, wq, 3145728);
    CONV(ow + (size_t)l * 1048576, wo, 1048576);
    CONV(rw + (size_t)l * 1048576, wr, 1048576);
    CONV(ffw1 + (size_t)l * 4194304, w1, 4194304);
    CONV(ffw2 + (size_t)l * 4194304, w2, 4194304);

    // qkv = cat @ qkv_w^T  (bf16 out)
    mgemm<4, 1, 0, 0><<<dim3(32, 24, 1), 256, 0, stream>>>(
        cat_bf, wq, qkv_bf, nullptr, 1024, 1024, 1024, 3072, 0, 0, 0, 0, 0, 0);
    // r = pe @ r_w^T  (bf16 out)
    mgemm<2, 1, 0, 0><<<dim3(16, 8, 1), 256, 0, stream>>>(
        pe_bf, wr, rb_bf, nullptr, 1024, 1024, 1024, 1024, 0, 0, 0, 0, 0, 0);

    qprep_kernel<<<dim3(QLEN, BATCH), 256, 0, stream>>>(
        qkv_bf, rwb + (size_t)l * ND, rrb + (size_t)l * ND, qa_bf, qb_bf);
    vtrans_kernel<<<dim3(16, 64), 256, 0, stream>>>(qkv_bf, Vt);

    for (int ng = 0; ng < 4; ++ng) {
      // AC[i,j] = qa_i . k_j   (f32 out)
      mgemm<4, 0, 0, 0><<<dim3(4, 8, 16), 256, 0, stream>>>(
          qa_bf + ng * 256, qkv_bf + 1024 + ng * 256, S_AC, nullptr, 64,
          1024, 12288, 1024, 524288, 64, 3072, 64, 524288, 2097152);
      // BDraw[i,s] = qb_i . r_s   (f32 out)
      mgemm<4, 0, 0, 0><<<dim3(4, 8, 16), 256, 0, stream>>>(
          qb_bf + ng * 256, rb_bf + ng * 256, S_BD, nullptr, 64,
          1024, 1024, 1024, 524288, 64, 0, 64, 524288, 2097152);
      attn_softmax<<<dim3(QLEN, 4, BATCH), 256, 0, stream>>>(S_AC, S_BD, (u16*)S_AC);
      // vec = P @ Vt^T
      mgemm_pv<<<dim3(4, 1, 16), 256, 0, stream>>>(
          (u16*)S_AC, Vt + (size_t)ng * 262144, vec_bf + ng * 256, 1024,
          2048, 1024, 4096, 1048576, 4194304, 1048576, 65536, 1024, 64);
    }

    // o-proj (f32 out into tmp)
    mgemm<2, 0, 0, 0><<<dim3(32, 8, 1), 256, 0, stream>>>(
        vec_bf, wo, tmp, nullptr, 1024, 1024, 1024, 1024, 0, 0, 0, 0, 0, 0);
    ln_residual_kernel<<<2048, 256, 0, stream>>>(
        h, h_bf, tmp, ln1g + (size_t)l * DMODEL, ln1b + (size_t)l * DMODEL);
    // FFN1 (bf16 out, bias+relu)
    mgemm<4, 1, 1, 1><<<dim3(16, 32, 1), 256, 0, stream>>>(
        h_bf, w1, ffh_bf, ffb1 + (size_t)l * DINNER, 1024,
        1024, 1024, 4096, 0, 0, 0, 0, 0, 0);
    // FFN2 (f32 out, bias)
    mgemm<2, 0, 0, 1><<<dim3(32, 8, 1), 256, 0, stream>>>(
        ffh_bf, w2, tmp, ffb2 + (size_t)l * DMODEL, 4096,
        4096, 4096, 1024, 0, 0, 0, 0, 0, 0);
    ln_residual_kernel<<<2048, 256, 0, stream>>>(
        h, h_bf, tmp, ln2g + (size_t)l * DMODEL, ln2b + (size_t)l * DMODEL);
  }

  out_kernel<<<dim3(QLEN, BATCH), 256, 0, stream>>>(h, (float*)d_out);
}

// Round 5
// 1219.263 us; speedup vs baseline: 11.7195x; 1.4910x over previous
//
#include <hip/hip_runtime.h>
#include <cstdint>

#define NLAYER 4
#define DMODEL 1024
#define NHEAD 16
#define DHEAD 64
#define DINNER 4096
#define QLEN 512
#define MLEN 512
#define KLEN (QLEN + MLEN)
#define BATCH 4
#define ND (NHEAD * DHEAD)

typedef unsigned short u16;
typedef __attribute__((ext_vector_type(8))) short short8;
typedef __attribute__((ext_vector_type(4))) float f32x4;

__device__ __forceinline__ u16 f2b(float x) {
  unsigned u = __builtin_bit_cast(unsigned, x);
  return (u16)((u + 0x7fffu + ((u >> 16) & 1u)) >> 16);
}
__device__ __forceinline__ float b2f(u16 h) {
  return __builtin_bit_cast(float, (unsigned)h << 16);
}

// ---------------- f32 -> bf16 bulk convert ----------------
__global__ __launch_bounds__(256) void conv_bf16(
    const float* __restrict__ s, u16* __restrict__ d, int n8)
{
  const int i = blockIdx.x * 256 + threadIdx.x;
  if (i >= n8) return;
  const float4 a = ((const float4*)s)[2 * i], b = ((const float4*)s)[2 * i + 1];
  union { u16 u[8]; float4 v; } p;
  p.u[0] = f2b(a.x); p.u[1] = f2b(a.y); p.u[2] = f2b(a.z); p.u[3] = f2b(a.w);
  p.u[4] = f2b(b.x); p.u[5] = f2b(b.y); p.u[6] = f2b(b.z); p.u[7] = f2b(b.w);
  ((float4*)d)[i] = p.v;
}

// ---------------- embedding gather ----------------
__global__ __launch_bounds__(256) void embed_kernel(
    const int* __restrict__ tok, const float* __restrict__ emb,
    float* __restrict__ h, u16* __restrict__ hb)
{
  const int q = blockIdx.x, b = blockIdx.y, t = threadIdx.x;
  const int id = tok[b * QLEN + q];
  const float4 v = ((const float4*)(emb + (size_t)id * DMODEL))[t];
  const size_t row = (size_t)q * BATCH + b;
  ((float4*)(h + row * DMODEL))[t] = v;
  union { u16 u[4]; float2 f; } p;
  p.u[0] = f2b(v.x); p.u[1] = f2b(v.y); p.u[2] = f2b(v.z); p.u[3] = f2b(v.w);
  *(float2*)(hb + row * DMODEL + t * 4) = p.f;
}

// ---------------- sinusoidal pos emb (bf16 out) ----------------
__global__ __launch_bounds__(256) void posemb_kernel(u16* __restrict__ pe)
{
  const int k = blockIdx.x, t = threadIdx.x;
  const float pos = (float)(KLEN - 1 - k);
  for (int i = t; i < DMODEL / 2; i += 256) {
    const float inv_freq = powf(10000.0f, -(float)(2 * i) / (float)DMODEL);
    const float a = pos * inv_freq;
    pe[(size_t)k * DMODEL + i] = f2b(sinf(a));
    pe[(size_t)k * DMODEL + DMODEL / 2 + i] = f2b(cosf(a));
  }
}

// ---------------- MFMA NT GEMM (same as validated round-4 version) ----------------
template<int MF, int OUTBF, int RELU, int BIAS>
__global__ __launch_bounds__(256) void mgemm(
    const u16* __restrict__ A, const u16* __restrict__ B, void* __restrict__ Cp,
    const float* __restrict__ bias, int Kd,
    long sa, long sb, long sc,
    long azb, long azn, long bzb, long bzn, long czb, long czn)
{
  constexpr int BM = MF * 32;
  __shared__ u16 As[BM][40];
  __shared__ u16 Bs[128][40];
  const int z = blockIdx.z, zb = z & 3, zn = z >> 2;
  A += (size_t)zb * azb + (size_t)zn * azn;
  B += (size_t)zb * bzb + (size_t)zn * bzn;
  const size_t bm = (size_t)blockIdx.x * BM, bn = (size_t)blockIdx.y * 128;
  const int t = threadIdx.x;
  const int wave = t >> 6, lane = t & 63;
  const int wm = (wave >> 1) * (MF * 16), wn = (wave & 1) * 64;
  const int lrow = lane & 15, lk = lane >> 4;
  const int srow = t >> 2, skc = (t & 3) * 8;
  const u16* Ap = A + (bm + srow) * sa + skc;
  const u16* Bp = B + (bn + srow) * sb + skc;
  f32x4 acc[MF][4] = {};
  for (int k0 = 0; k0 < Kd; k0 += 32) {
    float4 a0, a1;
    a0 = *(const float4*)(Ap + k0);
    if (MF == 4) a1 = *(const float4*)(Ap + 64 * sa + k0);
    const float4 b0 = *(const float4*)(Bp + k0);
    const float4 b1 = *(const float4*)(Bp + 64 * sb + k0);
    __syncthreads();
    if (srow < BM) *(float4*)&As[srow][skc] = a0;
    if (MF == 4) *(float4*)&As[(srow + 64) & (BM - 1)][skc] = a1;
    *(float4*)&Bs[srow][skc] = b0;
    *(float4*)&Bs[srow + 64][skc] = b1;
    __syncthreads();
    short8 af[MF], bf[4];
#pragma unroll
    for (int x = 0; x < MF; ++x) af[x] = *(const short8*)&As[wm + x * 16 + lrow][lk * 8];
#pragma unroll
    for (int x = 0; x < 4; ++x) bf[x] = *(const short8*)&Bs[wn + x * 16 + lrow][lk * 8];
#pragma unroll
    for (int mi = 0; mi < MF; ++mi)
#pragma unroll
      for (int ni = 0; ni < 4; ++ni)
        acc[mi][ni] = __builtin_amdgcn_mfma_f32_16x16x32_bf16(af[mi], bf[ni], acc[mi][ni], 0, 0, 0);
  }
  const size_t row0 = bm + wm + lk * 4;
  const size_t col0 = bn + wn + lrow;
  if (OUTBF) {
    u16* C = (u16*)Cp + (size_t)zb * czb + (size_t)zn * czn;
#pragma unroll
    for (int mi = 0; mi < MF; ++mi)
#pragma unroll
      for (int r = 0; r < 4; ++r) {
        const size_t row = row0 + mi * 16 + r;
#pragma unroll
        for (int ni = 0; ni < 4; ++ni) {
          float v = acc[mi][ni][r];
          if (BIAS) v += bias[col0 + ni * 16];
          if (RELU) v = fmaxf(v, 0.0f);
          C[row * sc + col0 + ni * 16] = f2b(v);
        }
      }
  } else {
    float* C = (float*)Cp + (size_t)zb * czb + (size_t)zn * czn;
#pragma unroll
    for (int mi = 0; mi < MF; ++mi)
#pragma unroll
      for (int r = 0; r < 4; ++r) {
        const size_t row = row0 + mi * 16 + r;
#pragma unroll
        for (int ni = 0; ni < 4; ++ni) {
          float v = acc[mi][ni][r];
          if (BIAS) v += bias[col0 + ni * 16];
          if (RELU) v = fmaxf(v, 0.0f);
          C[row * sc + col0 + ni * 16] = v;
        }
      }
  }
}

// ---------------- qa/qb prep ----------------
__global__ __launch_bounds__(256) void qprep_kernel(
    const u16* __restrict__ qkvb, const float* __restrict__ rwb,
    const float* __restrict__ rrb, u16* __restrict__ qa, u16* __restrict__ qb)
{
  const int i = blockIdx.x, b = blockIdx.y, t = threadIdx.x;
  const int c = t * 4;
  const size_t src = ((size_t)(QLEN + i) * BATCH + b) * (3 * ND) + c;
  const size_t dst = ((size_t)b * QLEN + i) * ND + c;
  union { u16 u[4]; float2 f; } qi, oa, ob;
  qi.f = *(const float2*)(qkvb + src);
#pragma unroll
  for (int e = 0; e < 4; ++e) {
    const float q = b2f(qi.u[e]);
    oa.u[e] = f2b(q + rwb[c + e]);
    ob.u[e] = f2b(q + rrb[c + e]);
  }
  *(float2*)(qa + dst) = oa.f;
  *(float2*)(qb + dst) = ob.f;
}

// ---------------- V transpose: qkv V -> Vt[b][n][d][j] ----------------
__global__ __launch_bounds__(256) void vtrans_kernel(
    const u16* __restrict__ qkvb, u16* __restrict__ Vt)
{
  __shared__ u16 T[64][72];
  const int j0 = blockIdx.x * 64;
  const int bn = blockIdx.y, b = bn >> 4, n = bn & 15;
  const int t = threadIdx.x;
  const int jl = t >> 3, ch = t & 7;
#pragma unroll
  for (int p = 0; p < 2; ++p) {
    const int jj = p * 32 + jl;
    const float4 v = *(const float4*)(qkvb + ((size_t)(j0 + jj) * BATCH + b) * (3 * ND)
                                      + 2 * ND + n * 64 + ch * 8);
    *(float4*)&T[jj][ch * 8] = v;
  }
  __syncthreads();
#pragma unroll
  for (int p = 0; p < 2; ++p) {
    const int dd = p * 32 + jl;
    union { u16 u[8]; float4 v; } o;
#pragma unroll
    for (int e = 0; e < 8; ++e) o.u[e] = T[ch * 8 + e][dd];
    *(float4*)(Vt + ((size_t)(b * 16 + n) * 64 + dd) * 1024 + j0 + ch * 8) = o.v;
  }
}

// ---------------- fused flash attention: AC + shifted-BD + softmax + PV ----------------
// grid (8 i-tiles, 16 heads, 4 batch), 256 threads = 4 waves, 16 i-rows/wave.
__global__ __launch_bounds__(256) void flash_attn(
    const u16* __restrict__ qa, const u16* __restrict__ qkvb,
    const u16* __restrict__ Vt, const float* __restrict__ BD,
    u16* __restrict__ O)
{
  __shared__ u16 qs[64][72];
  __shared__ u16 ks[64][72];
  __shared__ u16 vs[64][72];
  __shared__ u16 ps[4][16][72];
  const int i0 = blockIdx.x * 64;
  const int n = blockIdx.y, b = blockIdx.z;
  const int t = threadIdx.x, wave = t >> 6, lane = t & 63;
  const int lrow = lane & 15, lk = lane >> 4;
  const int sr = t >> 2, sc = (t & 3) * 8;
  {
    const u16* src = qa + ((size_t)b * QLEN + i0 + sr) * ND + n * 64;
    *(float4*)&qs[sr][sc] = *(const float4*)(src + sc);
    *(float4*)&qs[sr][sc + 32] = *(const float4*)(src + sc + 32);
  }
  const float* bd = BD + ((size_t)(n * 4 + b) * QLEN + i0) * 1024;
  f32x4 o[4] = {};
  float m[4] = {-INFINITY, -INFINITY, -INFINITY, -INFINITY};
  float l[4] = {0.0f, 0.0f, 0.0f, 0.0f};
  const int ntiles = blockIdx.x + 9;
  for (int jt = 0; jt < ntiles; ++jt) {
    const int j0 = jt * 64;
    const u16* ksrc = qkvb + ((size_t)(j0 + sr) * BATCH + b) * (3 * ND) + ND + n * 64;
    const u16* vsrc = Vt + ((size_t)(b * 16 + n) * 64 + sr) * 1024 + j0;
    const float4 k0v = *(const float4*)(ksrc + sc);
    const float4 k1v = *(const float4*)(ksrc + sc + 32);
    const float4 v0v = *(const float4*)(vsrc + sc);
    const float4 v1v = *(const float4*)(vsrc + sc + 32);
    __syncthreads();
    *(float4*)&ks[sr][sc] = k0v;  *(float4*)&ks[sr][sc + 32] = k1v;
    *(float4*)&vs[sr][sc] = v0v;  *(float4*)&vs[sr][sc + 32] = v1v;
    __syncthreads();
    // QK^T for this wave's 16 i-rows
    f32x4 s[4] = {};
    const short8 aq0 = *(const short8*)&qs[wave * 16 + lrow][lk * 8];
    const short8 aq1 = *(const short8*)&qs[wave * 16 + lrow][32 + lk * 8];
#pragma unroll
    for (int nf = 0; nf < 4; ++nf) {
      const short8 b0 = *(const short8*)&ks[nf * 16 + lrow][lk * 8];
      const short8 b1 = *(const short8*)&ks[nf * 16 + lrow][32 + lk * 8];
      s[nf] = __builtin_amdgcn_mfma_f32_16x16x32_bf16(aq0, b0, s[nf], 0, 0, 0);
      s[nf] = __builtin_amdgcn_mfma_f32_16x16x32_bf16(aq1, b1, s[nf], 0, 0, 0);
    }
    // add shifted BD, scale, causal mask  (C layout: row=lk*4+r, col=nf*16+lrow)
    float sv[4][4];
#pragma unroll
    for (int nf = 0; nf < 4; ++nf)
#pragma unroll
      for (int r = 0; r < 4; ++r) {
        const int il = wave * 16 + lk * 4 + r;
        const int ig = i0 + il;
        const int jg = j0 + nf * 16 + lrow;
        int p = jg - ig + 511;
        p = p > 1023 ? 1023 : p;
        const float bdv = bd[(size_t)il * 1024 + p];
        const float val = (s[nf][r] + bdv) * 0.125f;
        sv[nf][r] = (jg <= ig + MLEN) ? val : -INFINITY;
      }
    // online softmax
#pragma unroll
    for (int r = 0; r < 4; ++r) {
      float mt = fmaxf(fmaxf(sv[0][r], sv[1][r]), fmaxf(sv[2][r], sv[3][r]));
#pragma unroll
      for (int dx = 1; dx < 16; dx <<= 1) mt = fmaxf(mt, __shfl_xor(mt, dx));
      const float mnew = fmaxf(m[r], mt);
      const float alpha = __expf(m[r] - mnew);
      float ls = 0.0f;
#pragma unroll
      for (int nf = 0; nf < 4; ++nf) {
        const float pv = __expf(sv[nf][r] - mnew);
        sv[nf][r] = pv;
        ls += pv;
      }
#pragma unroll
      for (int dx = 1; dx < 16; dx <<= 1) ls += __shfl_xor(ls, dx);
      l[r] = l[r] * alpha + ls;
      m[r] = mnew;
#pragma unroll
      for (int nf = 0; nf < 4; ++nf) o[nf][r] *= alpha;
    }
    // P (C layout) -> per-wave LDS -> A-fragment layout
#pragma unroll
    for (int nf = 0; nf < 4; ++nf)
#pragma unroll
      for (int r = 0; r < 4; ++r)
        ps[wave][lk * 4 + r][nf * 16 + lrow] = f2b(sv[nf][r]);
    asm volatile("s_waitcnt lgkmcnt(0)" ::: "memory");
    __builtin_amdgcn_sched_barrier(0);
    const short8 pa0 = *(const short8*)&ps[wave][lrow][lk * 8];
    const short8 pa1 = *(const short8*)&ps[wave][lrow][32 + lk * 8];
#pragma unroll
    for (int nf = 0; nf < 4; ++nf) {
      const short8 b0 = *(const short8*)&vs[nf * 16 + lrow][lk * 8];
      const short8 b1 = *(const short8*)&vs[nf * 16 + lrow][32 + lk * 8];
      o[nf] = __builtin_amdgcn_mfma_f32_16x16x32_bf16(pa0, b0, o[nf], 0, 0, 0);
      o[nf] = __builtin_amdgcn_mfma_f32_16x16x32_bf16(pa1, b1, o[nf], 0, 0, 0);
    }
  }
#pragma unroll
  for (int r = 0; r < 4; ++r) {
    const float inv = 1.0f / l[r];
    const size_t ig = i0 + wave * 16 + lk * 4 + r;
#pragma unroll
    for (int nf = 0; nf < 4; ++nf)
      O[(ig * BATCH + b) * ND + n * 64 + nf * 16 + lrow] = f2b(o[nf][r] * inv);
  }
}

// ---------------- fused residual + LayerNorm ----------------
__global__ __launch_bounds__(256) void ln_residual_kernel(
    float* __restrict__ h, u16* __restrict__ hb, const float* __restrict__ delta,
    const float* __restrict__ g, const float* __restrict__ bb)
{
  const int row = blockIdx.x, t = threadIdx.x;
  __shared__ float xs[DMODEL];
  __shared__ float red[256];
  float s = 0.0f;
  for (int d = t; d < DMODEL; d += 256) {
    const float v = h[(size_t)row * DMODEL + d] + delta[(size_t)row * DMODEL + d];
    xs[d] = v;
    s += v;
  }
  red[t] = s;
  __syncthreads();
  for (int w = 128; w > 0; w >>= 1) {
    if (t < w) red[t] += red[t + w];
    __syncthreads();
  }
  const float mean = red[0] * (1.0f / DMODEL);
  __syncthreads();
  float vs = 0.0f;
  for (int d = t; d < DMODEL; d += 256) {
    const float dv = xs[d] - mean;
    vs = fmaf(dv, dv, vs);
  }
  red[t] = vs;
  __syncthreads();
  for (int w = 128; w > 0; w >>= 1) {
    if (t < w) red[t] += red[t + w];
    __syncthreads();
  }
  const float rstd = rsqrtf(red[0] * (1.0f / DMODEL) + 1e-5f);
  for (int d = t; d < DMODEL; d += 256) {
    const float o = (xs[d] - mean) * rstd * g[d] + bb[d];
    h[(size_t)row * DMODEL + d] = o;
    hb[(size_t)row * DMODEL + d] = f2b(o);
  }
}

// ---------------- output transpose ----------------
__global__ __launch_bounds__(256) void out_kernel(
    const float* __restrict__ h, float* __restrict__ out)
{
  const int q = blockIdx.x, b = blockIdx.y, t = threadIdx.x;
  const float4* src = (const float4*)(h + ((size_t)q * BATCH + b) * DMODEL);
  float4* dst = (float4*)(out + ((size_t)b * QLEN + q) * DMODEL);
  dst[t] = src[t];
}

extern "C" void kernel_launch(void* const* d_in, const int* in_sizes, int n_in,
                              void* d_out, int out_size, void* d_ws, size_t ws_size,
                              hipStream_t stream)
{
  const int*   tok  = (const int*)d_in[0];
  const float* mems = (const float*)d_in[1];
  const float* wemb = (const float*)d_in[2];
  const float* qkvw = (const float*)d_in[3];
  const float* ow   = (const float*)d_in[4];
  const float* rw   = (const float*)d_in[5];
  const float* rwb  = (const float*)d_in[6];
  const float* rrb  = (const float*)d_in[7];
  const float* ln1g = (const float*)d_in[8];
  const float* ln1b = (const float*)d_in[9];
  const float* ffw1 = (const float*)d_in[10];
  const float* ffb1 = (const float*)d_in[11];
  const float* ffw2 = (const float*)d_in[12];
  const float* ffb2 = (const float*)d_in[13];
  const float* ln2g = (const float*)d_in[14];
  const float* ln2b = (const float*)d_in[15];

  float* h    = (float*)d_ws;                 // [2048][1024] f32
  float* S    = h + 2097152;                  // BDraw [64][512][1024] f32 (134 MB)
  float* tmp  = S;                            // alias (BDraw dead after flash)
  u16* cat_bf = (u16*)(S + 33554432);         // [4096][1024]
  u16* h_bf   = cat_bf + 2097152;
  u16* qkv_bf = cat_bf + 4194304;             // [4096][3072]
  u16* ffh_bf = qkv_bf;                       // alias (qkv dead after attention)
  u16* pe_bf  = qkv_bf + 12582912;            // [1024][1024]
  u16* rb_bf  = pe_bf + 1048576;              // [1024][1024]
  u16* qa_bf  = rb_bf + 1048576;              // [4][512][1024]
  u16* qb_bf  = qa_bf + 2097152;
  u16* Vt     = qb_bf + 2097152;              // [4][16][64][1024]
  u16* vec_bf = Vt + 4194304;                 // [2048][1024]
  u16* wq = vec_bf + 2097152;                 // [3072][1024]
  u16* wo = wq + 3145728;
  u16* wr = wo + 1048576;
  u16* w1 = wr + 1048576;                     // [4096][1024]
  u16* w2 = w1 + 4194304;                     // [1024][4096]

  embed_kernel<<<dim3(QLEN, BATCH), 256, 0, stream>>>(tok, wemb, h, h_bf);
  posemb_kernel<<<KLEN, 256, 0, stream>>>(pe_bf);

#define CONV(src, dst, n) conv_bf16<<<(n) / 2048, 256, 0, stream>>>(src, dst, (n) / 8)

  for (int l = 0; l < NLAYER; ++l) {
    CONV(mems + (size_t)l * 2097152, cat_bf, 2097152);
    CONV(qkvw + (size_t)l * 3145728, wq, 3145728);
    CONV(ow + (size_t)l * 1048576, wo, 1048576);
    CONV(rw + (size_t)l * 1048576, wr, 1048576);
    CONV(ffw1 + (size_t)l * 4194304, w1, 4194304);
    CONV(ffw2 + (size_t)l * 4194304, w2, 4194304);

    // qkv = cat @ qkv_w^T  (bf16 out)
    mgemm<4, 1, 0, 0><<<dim3(32, 24, 1), 256, 0, stream>>>(
        cat_bf, wq, qkv_bf, nullptr, 1024, 1024, 1024, 3072, 0, 0, 0, 0, 0, 0);
    // r = pe @ r_w^T  (bf16 out)
    mgemm<2, 1, 0, 0><<<dim3(16, 8, 1), 256, 0, stream>>>(
        pe_bf, wr, rb_bf, nullptr, 1024, 1024, 1024, 1024, 0, 0, 0, 0, 0, 0);

    qprep_kernel<<<dim3(QLEN, BATCH), 256, 0, stream>>>(
        qkv_bf, rwb + (size_t)l * ND, rrb + (size_t)l * ND, qa_bf, qb_bf);
    vtrans_kernel<<<dim3(16, 64), 256, 0, stream>>>(qkv_bf, Vt);

    // BDraw[n*4+b][i][s] = qb_i . r_s   (all 64 slices, one dispatch)
    mgemm<4, 0, 0, 0><<<dim3(4, 8, 64), 256, 0, stream>>>(
        qb_bf, rb_bf, S, nullptr, 64,
        1024, 1024, 1024, 524288, 64, 0, 64, 524288, 2097152);

    // fused attention
    flash_attn<<<dim3(8, 16, 4), 256, 0, stream>>>(qa_bf, qkv_bf, Vt, S, vec_bf);

    // o-proj (f32 out into tmp)
    mgemm<2, 0, 0, 0><<<dim3(32, 8, 1), 256, 0, stream>>>(
        vec_bf, wo, tmp, nullptr, 1024, 1024, 1024, 1024, 0, 0, 0, 0, 0, 0);
    ln_residual_kernel<<<2048, 256, 0, stream>>>(
        h, h_bf, tmp, ln1g + (size_t)l * DMODEL, ln1b + (size_t)l * DMODEL);
    // FFN1 (bf16 out, bias+relu)
    mgemm<4, 1, 1, 1><<<dim3(16, 32, 1), 256, 0, stream>>>(
        h_bf, w1, ffh_bf, ffb1 + (size_t)l * DINNER, 1024,
        1024, 1024, 4096, 0, 0, 0, 0, 0, 0);
    // FFN2 (f32 out, bias)
    mgemm<2, 0, 0, 1><<<dim3(32, 8, 1), 256, 0, stream>>>(
        ffh_bf, w2, tmp, ffb2 + (size_t)l * DMODEL, 4096,
        4096, 4096, 1024, 0, 0, 0, 0, 0, 0);
    ln_residual_kernel<<<2048, 256, 0, stream>>>(
        h, h_bf, tmp, ln2g + (size_t)l * DMODEL, ln2b + (size_t)l * DMODEL);
  }

  out_kernel<<<dim3(QLEN, BATCH), 256, 0, stream>>>(h, (float*)d_out);
}